// Round 3
// baseline (1858.785 us; speedup 1.0000x reference)
//
#include <hip/hip_runtime.h>
#include <cstddef>

// B=2 T=512 D=512 V=256 MEM=256 ; M = B*T = 1024
// All inputs fp32 (x is int32); all outputs fp32.
#define F_ELUQK 1
#define F_CAUSAL 2
#define F_DIV 4
#define F_NN 8
#define F_SCALE 16
#define F_ROWSUM 32
#define FLAG_STRIDE 32   // u32 units -> 128 B per WG flag line
#define L_WGS 64         // WGs per GRU layer
#define UNITS 8          // hidden units per WG

// ---------- ws layout (float units) ----------
enum : int {
  OFF_QH = 0,                          // [1024][512] hip query / axon K-chunk-1 acc
  OFF_COMB = 524288,                   // [1024][2048]  p_f | intent | l_mem | episodes
  OFF_PS = OFF_COMB + 2097152,         // [1024][512]
  OFF_QKV = OFF_PS + 524288,           // [1024][1536]  q(elu+1) | k(elu+1) | v
  OFF_SCORES = OFF_QKV + 1572864,      // [1024][512]
  OFF_DEN = OFF_SCORES + 524288,       // [1024]
  OFF_TMP = OFF_DEN + 1024,            // [1024][512]
  OFF_ATTN = OFF_TMP + 524288,         // [1024][256]
  OFF_SWN = OFF_ATTN + 262144,         // [256] 16/||soma_row||
  OFF_RING = OFF_SWN + 256,            // ull[4][1024] tagged h_f ring (8192 floats)
  OFF_HSB = OFF_RING + 8192,           // ull[2][1024] tagged h_s dbuf (4096 floats)
  OFF_FLAGS = OFF_HSB + 4096           // flagsA[64*32] | flagsB[64*32] u32 (16 KB)
};

// raw workgroup barrier: LDS visibility only (lgkmcnt), NO vmcnt drain.
// Every LDS-writing wave drains its own lgkmcnt here; outstanding global
// stores (pf_out/ps_out, flag posts) stay in flight across it.
#define BAR() __asm__ __volatile__("s_waitcnt lgkmcnt(0)\n\ts_barrier" ::: "memory")

// ---------- generic tiled GEMM:  C[m, coff+n] = sum_k A(m,k) * B(n,k)  (+epilogue) ----------
__global__ __launch_bounds__(256) void gemm(
    const float* __restrict__ A, int lda, const float* __restrict__ B, int ldb,
    float* __restrict__ C, int ldc, int coff, int K,
    const float* __restrict__ bias, const float* __restrict__ den,
    const float* __restrict__ cscale, float* __restrict__ rsum,
    float scale, int flags, int bBatch,
    float* __restrict__ Cz, int kzoff) {
  __shared__ float As[16 * 65];
  __shared__ float Bs[16 * 65];
  int tid = threadIdx.x;
  int n0 = blockIdx.x * 64, m0 = blockIdx.y * 64;
  if (blockIdx.z) { A += kzoff; B += kzoff; C = Cz; bias = nullptr; }
  int rowoff = (m0 >> 9) * bBatch;
  int tx = tid & 15, ty = tid >> 4;

  if ((flags & F_CAUSAL) && n0 > ((m0 & 511) + 63)) {
    #pragma unroll
    for (int i = 0; i < 4; ++i)
      #pragma unroll
      for (int j = 0; j < 4; ++j)
        C[(size_t)(m0 + ty * 4 + i) * ldc + coff + n0 + tx * 4 + j] = 0.f;
    return;
  }

  float acc[4][4] = {};
  for (int k0 = 0; k0 < K; k0 += 16) {
    {
      int rr = tid >> 2, c4 = (tid & 3) << 2;
      const float* ap = A + (size_t)(m0 + rr) * lda + (k0 + c4);
      float4 av = *(const float4*)ap;
      As[(c4 + 0) * 65 + rr] = av.x;
      As[(c4 + 1) * 65 + rr] = av.y;
      As[(c4 + 2) * 65 + rr] = av.z;
      As[(c4 + 3) * 65 + rr] = av.w;
    }
    if (!(flags & F_NN)) {
      int rr = tid >> 2, c4 = (tid & 3) << 2;
      const float* bp = B + (size_t)(n0 + rr + rowoff) * ldb + (k0 + c4);
      float4 bv = *(const float4*)bp;
      Bs[(c4 + 0) * 65 + rr] = bv.x; Bs[(c4 + 1) * 65 + rr] = bv.y;
      Bs[(c4 + 2) * 65 + rr] = bv.z; Bs[(c4 + 3) * 65 + rr] = bv.w;
    } else {
      int kk = tid >> 4, n4 = (tid & 15) << 2;
      const float* bp = B + (size_t)(k0 + kk + rowoff) * ldb + (n0 + n4);
      float4 bv = *(const float4*)bp;
      Bs[kk * 65 + n4 + 0] = bv.x; Bs[kk * 65 + n4 + 1] = bv.y;
      Bs[kk * 65 + n4 + 2] = bv.z; Bs[kk * 65 + n4 + 3] = bv.w;
    }
    __syncthreads();
    #pragma unroll
    for (int k = 0; k < 16; ++k) {
      float av[4], bv[4];
      #pragma unroll
      for (int i = 0; i < 4; ++i) av[i] = As[k * 65 + ty * 4 + i];
      #pragma unroll
      for (int j = 0; j < 4; ++j) bv[j] = Bs[k * 65 + tx * 4 + j];
      #pragma unroll
      for (int i = 0; i < 4; ++i)
        #pragma unroll
        for (int j = 0; j < 4; ++j)
          acc[i][j] = fmaf(av[i], bv[j], acc[i][j]);
    }
    __syncthreads();
  }
  float rs[4] = {0.f, 0.f, 0.f, 0.f};
  #pragma unroll
  for (int i = 0; i < 4; ++i) {
    int m = m0 + ty * 4 + i;
    float dv = (flags & F_DIV) ? (1.0f / (den[m] + 1e-6f)) : 1.0f;
    #pragma unroll
    for (int j = 0; j < 4; ++j) {
      int n = n0 + tx * 4 + j;
      float v = acc[i][j];
      if (bias) v += bias[n];
      if (flags & F_ELUQK) { if (n < 1024) v = (v > 0.f) ? (v + 1.f) : __expf(v); }
      if (flags & F_CAUSAL) { if (n > (m & 511)) v = 0.f; }
      if (flags & F_SCALE) v *= scale;
      if (cscale) v *= cscale[coff + n];
      if (flags & F_DIV) v *= dv;
      C[(size_t)m * ldc + coff + n] = v;
      if (flags & F_ROWSUM) rs[i] += v;
    }
  }
  if (flags & F_ROWSUM) {
    #pragma unroll
    for (int i = 0; i < 4; ++i) {
      float s = rs[i];
      s += __shfl_xor(s, 1); s += __shfl_xor(s, 2);
      s += __shfl_xor(s, 4); s += __shfl_xor(s, 8);
      if (tx == 0) atomicAdd(rsum + (m0 + ty * 4 + i), s);
    }
  }
}

// ---------- merged qkv / gate / hip_q projections (A = PS, K=512, NT) ----------
__global__ __launch_bounds__(256) void gemm3(
    const float* __restrict__ A,
    const float* __restrict__ qkvw, const float* __restrict__ qkvb,
    const float* __restrict__ gatew, const float* __restrict__ gateb,
    const float* __restrict__ hipw, const float* __restrict__ hipb,
    float* __restrict__ QKV, float* __restrict__ TMP, float* __restrict__ QH) {
  __shared__ float As[16 * 65];
  __shared__ float Bs[16 * 65];
  int tid = threadIdx.x;
  int n0 = blockIdx.x * 64, m0 = blockIdx.y * 64;
  const float* B; const float* bias; float* C; int ldc, base;
  if (n0 < 1536) { B = qkvw; bias = qkvb; C = QKV; ldc = 1536; base = 0; }
  else if (n0 < 2048) { B = gatew; bias = gateb; C = TMP; ldc = 512; base = 1536; }
  else { B = hipw; bias = hipb; C = QH; ldc = 512; base = 2048; }
  int tx = tid & 15, ty = tid >> 4;
  float acc[4][4] = {};
  for (int k0 = 0; k0 < 512; k0 += 16) {
    {
      int rr = tid >> 2, c4 = (tid & 3) << 2;
      const float* ap = A + (size_t)(m0 + rr) * 512 + (k0 + c4);
      float4 av = *(const float4*)ap;
      As[(c4 + 0) * 65 + rr] = av.x; As[(c4 + 1) * 65 + rr] = av.y;
      As[(c4 + 2) * 65 + rr] = av.z; As[(c4 + 3) * 65 + rr] = av.w;
    }
    {
      int rr = tid >> 2, c4 = (tid & 3) << 2;
      const float* bp = B + (size_t)(n0 - base + rr) * 512 + (k0 + c4);
      float4 bv = *(const float4*)bp;
      Bs[(c4 + 0) * 65 + rr] = bv.x; Bs[(c4 + 1) * 65 + rr] = bv.y;
      Bs[(c4 + 2) * 65 + rr] = bv.z; Bs[(c4 + 3) * 65 + rr] = bv.w;
    }
    __syncthreads();
    #pragma unroll
    for (int k = 0; k < 16; ++k) {
      float av[4], bv[4];
      #pragma unroll
      for (int i = 0; i < 4; ++i) av[i] = As[k * 65 + ty * 4 + i];
      #pragma unroll
      for (int j = 0; j < 4; ++j) bv[j] = Bs[k * 65 + tx * 4 + j];
      #pragma unroll
      for (int i = 0; i < 4; ++i)
        #pragma unroll
        for (int j = 0; j < 4; ++j)
          acc[i][j] = fmaf(av[i], bv[j], acc[i][j]);
    }
    __syncthreads();
  }
  #pragma unroll
  for (int i = 0; i < 4; ++i) {
    int m = m0 + ty * 4 + i;
    #pragma unroll
    for (int j = 0; j < 4; ++j) {
      int n = n0 + tx * 4 + j;
      float v = acc[i][j] + bias[n - base];
      if (n < 1024) v = (v > 0.f) ? (v + 1.f) : __expf(v);
      C[(size_t)m * ldc + (n - base)] = v;
    }
  }
}

// ---------- flag helpers (relaxed agent ops only) ----------
__device__ __forceinline__ void post_flag(unsigned* flags, int w, unsigned v) {
  __hip_atomic_store(flags + (size_t)w * FLAG_STRIDE, v, __ATOMIC_RELAXED,
                     __HIP_MEMORY_SCOPE_AGENT);
}
__device__ __forceinline__ void poll64(const unsigned* flags, unsigned tgt, int lane) {
  const unsigned* p = flags + (size_t)lane * FLAG_STRIDE;
  while (__hip_atomic_load(p, __ATOMIC_RELAXED, __HIP_MEMORY_SCOPE_AGENT) < tgt)
    __builtin_amdgcn_s_sleep(1);
}
// stage_pull: ONE speculative tag-validated sweep (1 L3 RTT on hit; steady
// state is lockstepped so producers' tagged stores are normally already
// visible). On a miss: fall back to the cheap 128B flag poll, then the
// validated retry loop (round-2 path). Bounded speculation — round 1 proved
// UNBOUNDED sweeping livelocks at cold start; one failed 8KB sweep is noise.
__device__ __forceinline__ void stage_pull(const unsigned long long* __restrict__ src,
                                           const unsigned* __restrict__ flags,
                                           unsigned tgt, int lane,
                                           float* __restrict__ dstLds) {
  unsigned long long v[16];
  #pragma unroll
  for (int k = 0; k < 16; ++k)
    v[k] = __hip_atomic_load(src + k * 64 + lane, __ATOMIC_RELAXED,
                             __HIP_MEMORY_SCOPE_AGENT);
  unsigned bad = 0;
  #pragma unroll
  for (int k = 0; k < 16; ++k) bad |= ((unsigned)(v[k] >> 32)) ^ tgt;
  if (!__all(bad == 0)) {
    poll64(flags, tgt, lane);
    for (;;) {
      #pragma unroll
      for (int k = 0; k < 16; ++k)
        v[k] = __hip_atomic_load(src + k * 64 + lane, __ATOMIC_RELAXED,
                                 __HIP_MEMORY_SCOPE_AGENT);
      bad = 0;
      #pragma unroll
      for (int k = 0; k < 16; ++k) bad |= ((unsigned)(v[k] >> 32)) ^ tgt;
      if (__all(bad == 0)) break;
      __builtin_amdgcn_s_sleep(1);
    }
  }
  #pragma unroll
  for (int k = 0; k < 16; ++k)
    dstLds[k * 64 + lane] = __uint_as_float((unsigned)v[k]);
}

// ---------- fused two-layer pipelined GRU, register-resident weights ----------
// 128 WGs: 0..63 layer1 (fast), 64..127 layer2 (slow, lags ~1 round).
// ROLES: waves 0-2 (tid 0..191, r<24) = pure compute. wave 3 = stager+gates.
// PROTOCOL (speculative tag + flag fallback): producer (wave3 lanes<16)
// computes gates, fires TAGGED 8B data stores (tag = step+1 in high word)
// and posts the flag immediately — NO vmcnt drain on the chain. Consumers
// first try ONE tag-validated sweep of the data itself (1 RTT on hit);
// only on a stale tag do they poll the 128B flag line and re-sweep
// (round-2 path). Bounded speculation avoids round-1's livelock.
// SCHEDULE (2 barriers/step):
//   phase A: wave3 stages h(t-1) (stage_pull -> hl)
//            || waves0-2 compute gi-dot (input side, no h dependency)
//   B1
//   phase B: waves0-2 gh-dot + reduce -> P,Q
//            || wave3 prefetches next input (s_in(t+1) / ring(t2+1)) + flagsB
//   B2
//   gates:   wave3 lanes<16: gate math, tagged ring/hsq store, flag post,
//            pf/ps_out stores — overlaps waves0-2 already running next gi-dot.
// Barriers are raw s_barrier + lgkmcnt(0) (LDS visibility only); no vmcnt
// drain anywhere in the loop.
// Skew safety: a WG passes its step-t stage only when ALL peers' step-t tags
// (or flags) are visible, so peers never exceed each other's step; ring slot
// s is rewritten at step s+4 gated by flagsB(s+1). Tags are 1-based; host
// zeroes ring/hsb/flags per launch, so stale tags never validate.
__global__ __launch_bounds__(256, 1) void gru2_kernel(
    const float* __restrict__ soma, const int* __restrict__ x,
    const float* __restrict__ fwih, const float* __restrict__ fbih,
    const float* __restrict__ fwhh, const float* __restrict__ fbhh,
    const float* __restrict__ h0f,
    const float* __restrict__ swih, const float* __restrict__ sbih,
    const float* __restrict__ swhh, const float* __restrict__ sbhh,
    const float* __restrict__ h0s,
    float* __restrict__ pf_out,         // COMB cols [0,512), ld 2048
    float* __restrict__ ps_out,         // PS, ld 512
    float* __restrict__ hfT, float* __restrict__ hsT,
    unsigned long long* __restrict__ ringq,   // [4][1024] tagged h_f
    unsigned long long* __restrict__ hsq,     // [2][1024] tagged h_s
    unsigned* __restrict__ flagsA, unsigned* __restrict__ flagsB) {
  __shared__ __attribute__((aligned(16))) float hl[1024];    // own-layer h(t-1)
  __shared__ __attribute__((aligned(16))) float inb[2048];   // input dbuf (s_in or p_f)
  __shared__ float P[48];
  __shared__ float Q[48];
  __shared__ float bl[24];
  __shared__ float bi[24];
  __shared__ int xl[1024];
  int tid = threadIdx.x, wg = blockIdx.x;
  bool L1 = wg < L_WGS;
  int j0 = (wg & (L_WGS - 1)) * UNITS;
  int part = tid & 7, r = tid >> 3;    // r in 0..31; compute lanes r<24
  int g = r >> 3, u = r & 7;           // gate, unit
  int wave = tid >> 6, lane = tid & 63;
  const float* whh = L1 ? fwhh : swhh;
  const float* bhh = L1 ? fbhh : sbhh;
  const float* wih = L1 ? fwih : swih;
  const float* bih = L1 ? fbih : sbih;

  float4 wh[16], wi[16];
  if (r < 24) {
    const float* wp = whh + (size_t)(g * 512 + j0 + u) * 512 + part * 4;
    #pragma unroll
    for (int i = 0; i < 16; ++i) wh[i] = *(const float4*)(wp + i * 32);
    const float* wp2 = wih + (size_t)(g * 512 + j0 + u) * 512 + part * 4;
    #pragma unroll
    for (int i = 0; i < 16; ++i) wi[i] = *(const float4*)(wp2 + i * 32);
  }
  if (tid < 24) {
    bl[tid] = bhh[(tid >> 3) * 512 + j0 + (tid & 7)];
    bi[tid] = bih[(tid >> 3) * 512 + j0 + (tid & 7)];
  }
  if (L1) {
    for (int q = tid; q < 1024; q += 256) xl[q] = x[q];
  }
  __syncthreads();

  // ---- pre-stage inb slot 0 (input for step 0) by wave 3 ----
  if (wave == 3) {
    if (L1) {
      int r0 = xl[0], r1 = xl[512];
      const float4* sp0 = (const float4*)(soma + (size_t)r0 * 512);
      const float4* sp1 = (const float4*)(soma + (size_t)r1 * 512);
      float4* dst = (float4*)inb;
      dst[lane * 2] = sp0[lane * 2]; dst[lane * 2 + 1] = sp0[lane * 2 + 1];
      dst[128 + lane * 2] = sp1[lane * 2]; dst[128 + lane * 2 + 1] = sp1[lane * 2 + 1];
    } else {
      stage_pull(ringq, flagsA, 1u, lane, inb);   // ring(0) -> inb slot 0
    }
  }
  BAR();

  const float4* h4 = (const float4*)hl;

  if (L1) {
    for (int t = 0; t < 512; ++t) {
      float c0 = 0.f, c1 = 0.f;
      // ---- PHASE A: stage h(t-1) || gi-dot ----
      if (wave == 3) {
        if (t == 0) {
          #pragma unroll
          for (int k = 0; k < 16; ++k) hl[k * 64 + lane] = h0f[k * 64 + lane];
        } else {
          stage_pull(ringq + (size_t)((t - 1) & 3) * 1024, flagsA,
                     (unsigned)t, lane, hl);
        }
      } else {
        const float4* f4v = (const float4*)(inb + (t & 1) * 1024);
        #pragma unroll
        for (int i = 0; i < 16; ++i) {
          float4 v = wi[i];
          float4 y0 = f4v[i * 8 + part];
          float4 y1 = f4v[128 + i * 8 + part];
          c0 += v.x * y0.x + v.y * y0.y + v.z * y0.z + v.w * y0.w;
          c1 += v.x * y1.x + v.y * y1.y + v.z * y1.z + v.w * y1.w;
        }
      }
      BAR();
      // ---- PHASE B: gh-dot + reduce || prefetch s_in(t+1) + flagsB ----
      if (wave != 3) {
        float a0 = 0.f, a1 = 0.f;
        #pragma unroll
        for (int i = 0; i < 16; ++i) {
          float4 w = wh[i];
          float4 x0 = h4[i * 8 + part];
          float4 x1 = h4[128 + i * 8 + part];
          a0 += w.x * x0.x + w.y * x0.y + w.z * x0.z + w.w * x0.w;
          a1 += w.x * x1.x + w.y * x1.y + w.z * x1.z + w.w * x1.w;
        }
        a0 += __shfl_xor(a0, 1); a0 += __shfl_xor(a0, 2); a0 += __shfl_xor(a0, 4);
        a1 += __shfl_xor(a1, 1); a1 += __shfl_xor(a1, 2); a1 += __shfl_xor(a1, 4);
        c0 += __shfl_xor(c0, 1); c0 += __shfl_xor(c0, 2); c0 += __shfl_xor(c0, 4);
        c1 += __shfl_xor(c1, 1); c1 += __shfl_xor(c1, 2); c1 += __shfl_xor(c1, 4);
        if (part == 0) { P[r] = a0; P[24 + r] = a1; Q[r] = c0; Q[24 + r] = c1; }
      } else {
        if (t + 1 < 512) {
          int r0 = xl[t + 1], r1 = xl[512 + t + 1];
          const float4* sp0 = (const float4*)(soma + (size_t)r0 * 512);
          const float4* sp1 = (const float4*)(soma + (size_t)r1 * 512);
          float4 p0 = sp0[lane * 2], p1 = sp0[lane * 2 + 1];
          float4 p2 = sp1[lane * 2], p3 = sp1[lane * 2 + 1];
          if (t >= 4) poll64(flagsB, (unsigned)(t - 3), lane);   // ring slot free
          float4* dst = (float4*)(inb + ((t + 1) & 1) * 1024);
          dst[lane * 2] = p0; dst[lane * 2 + 1] = p1;
          dst[128 + lane * 2] = p2; dst[128 + lane * 2 + 1] = p3;
        } else {
          if (t >= 4) poll64(flagsB, (unsigned)(t - 3), lane);
        }
      }
      BAR();
      // ---- GATES (wave3 lanes<16) — overlaps next phase A of waves0-2 ----
      if (wave == 3 && lane < 16) {
        int b = lane >> 3, u2 = lane & 7, j = j0 + u2;
        float i_r = Q[b * 24 + u2] + bi[u2];
        float i_z = Q[b * 24 + 8 + u2] + bi[8 + u2];
        float i_n = Q[b * 24 + 16 + u2] + bi[16 + u2];
        float gh_r = P[b * 24 + u2] + bl[u2];
        float gh_z = P[b * 24 + 8 + u2] + bl[8 + u2];
        float gh_n = P[b * 24 + 16 + u2] + bl[16 + u2];
        float hold = hl[b * 512 + j];
        float rg = 1.0f / (1.0f + __expf(-(i_r + gh_r)));
        float zg = 1.0f / (1.0f + __expf(-(i_z + gh_z)));
        float ng = tanhf(i_n + rg * gh_n);
        float hnew = (1.0f - zg) * ng + zg * hold;
        unsigned long long pv =
            ((unsigned long long)(unsigned)(t + 1) << 32) |
            (unsigned long long)__float_as_uint(hnew);
        __hip_atomic_store(ringq + (size_t)(t & 3) * 1024 + b * 512 + j, pv,
                           __ATOMIC_RELAXED, __HIP_MEMORY_SCOPE_AGENT);
        if (lane == 0) post_flag(flagsA, wg, (unsigned)(t + 1));
        pf_out[(size_t)(b * 512 + t) * 2048 + j] = hnew;
        if (t == 511) hfT[b * 512 + j] = hnew;
      }
      // no trailing barrier: wave3 flows into next phase-A staging; the next
      // B1 orders hl/P/Q reuse, and inb[(t+1)&1] was drained at B2 above.
    }
  } else {
    for (int t2 = 0; t2 < 512; ++t2) {
      float c0 = 0.f, c1 = 0.f;
      // ---- PHASE A: stage h_s(t2-1) || gi-dot on p_f(t2) ----
      if (wave == 3) {
        if (t2 == 0) {
          #pragma unroll
          for (int k = 0; k < 16; ++k) hl[k * 64 + lane] = h0s[k * 64 + lane];
        } else {
          stage_pull(hsq + (size_t)((t2 - 1) & 1) * 1024, flagsB,
                     (unsigned)t2, lane, hl);
        }
      } else {
        const float4* f4v = (const float4*)(inb + (t2 & 1) * 1024);
        #pragma unroll
        for (int i = 0; i < 16; ++i) {
          float4 v = wi[i];
          float4 y0 = f4v[i * 8 + part];
          float4 y1 = f4v[128 + i * 8 + part];
          c0 += v.x * y0.x + v.y * y0.y + v.z * y0.z + v.w * y0.w;
          c1 += v.x * y1.x + v.y * y1.y + v.z * y1.z + v.w * y1.w;
        }
      }
      BAR();
      // ---- PHASE B: gh-dot + reduce || stage ring(t2+1) ----
      if (wave != 3) {
        float a0 = 0.f, a1 = 0.f;
        #pragma unroll
        for (int i = 0; i < 16; ++i) {
          float4 w = wh[i];
          float4 x0 = h4[i * 8 + part];
          float4 x1 = h4[128 + i * 8 + part];
          a0 += w.x * x0.x + w.y * x0.y + w.z * x0.z + w.w * x0.w;
          a1 += w.x * x1.x + w.y * x1.y + w.z * x1.z + w.w * x1.w;
        }
        a0 += __shfl_xor(a0, 1); a0 += __shfl_xor(a0, 2); a0 += __shfl_xor(a0, 4);
        a1 += __shfl_xor(a1, 1); a1 += __shfl_xor(a1, 2); a1 += __shfl_xor(a1, 4);
        c0 += __shfl_xor(c0, 1); c0 += __shfl_xor(c0, 2); c0 += __shfl_xor(c0, 4);
        c1 += __shfl_xor(c1, 1); c1 += __shfl_xor(c1, 2); c1 += __shfl_xor(c1, 4);
        if (part == 0) { P[r] = a0; P[24 + r] = a1; Q[r] = c0; Q[24 + r] = c1; }
      } else {
        if (t2 + 1 < 512) {
          stage_pull(ringq + (size_t)((t2 + 1) & 3) * 1024, flagsA,
                     (unsigned)(t2 + 2), lane, inb + ((t2 + 1) & 1) * 1024);
        }
      }
      BAR();
      // ---- GATES (wave3 lanes<16) ----
      if (wave == 3 && lane < 16) {
        int b = lane >> 3, u2 = lane & 7, j = j0 + u2;
        float i_r = Q[b * 24 + u2] + bi[u2];
        float i_z = Q[b * 24 + 8 + u2] + bi[8 + u2];
        float i_n = Q[b * 24 + 16 + u2] + bi[16 + u2];
        float gh_r = P[b * 24 + u2] + bl[u2];
        float gh_z = P[b * 24 + 8 + u2] + bl[8 + u2];
        float gh_n = P[b * 24 + 16 + u2] + bl[16 + u2];
        float hold = hl[b * 512 + j];
        float rg = 1.0f / (1.0f + __expf(-(i_r + gh_r)));
        float zg = 1.0f / (1.0f + __expf(-(i_z + gh_z)));
        float ng = tanhf(i_n + rg * gh_n);
        float hnew = (1.0f - zg) * ng + zg * hold;
        unsigned long long pv =
            ((unsigned long long)(unsigned)(t2 + 1) << 32) |
            (unsigned long long)__float_as_uint(hnew);
        __hip_atomic_store(hsq + (size_t)(t2 & 1) * 1024 + b * 512 + j, pv,
                           __ATOMIC_RELAXED, __HIP_MEMORY_SCOPE_AGENT);
        if (lane == 0) post_flag(flagsB, wg - L_WGS, (unsigned)(t2 + 1));
        ps_out[(size_t)(b * 512 + t2) * 512 + j] = hnew;
        if (t2 == 511) hsT[b * 512 + j] = hnew;
      }
    }
  }
}

// ---------- small kernels ----------
__global__ __launch_bounds__(256) void softmax_kernel(float* __restrict__ a) {
  int m = blockIdx.x, tid = threadIdx.x;
  float v = a[(size_t)m * 256 + tid];
  float mx = v;
  #pragma unroll
  for (int off = 32; off > 0; off >>= 1) mx = fmaxf(mx, __shfl_down(mx, off));
  __shared__ float r4[4];
  __shared__ float s4[4];
  if ((tid & 63) == 0) r4[tid >> 6] = mx;
  __syncthreads();
  mx = fmaxf(fmaxf(r4[0], r4[1]), fmaxf(r4[2], r4[3]));
  float e = __expf(v - mx);
  float s = e;
  #pragma unroll
  for (int off = 32; off > 0; off >>= 1) s += __shfl_down(s, off);
  if ((tid & 63) == 0) s4[tid >> 6] = s;
  __syncthreads();
  s = s4[0] + s4[1] + s4[2] + s4[3];
  a[(size_t)m * 256 + tid] = e / s;
}

__global__ __launch_bounds__(256) void ln_kernel(
    const float* __restrict__ src, const float* __restrict__ src2,
    float* __restrict__ dst, int ldd, int dcoff,
    const float* __restrict__ gv, const float* __restrict__ bv, int tanhFirst) {
  int m = blockIdx.x, tid = threadIdx.x;
  float x0 = src[(size_t)m * 512 + tid];
  float x1 = src[(size_t)m * 512 + 256 + tid];
  if (src2) { x0 += src2[(size_t)m * 512 + tid]; x1 += src2[(size_t)m * 512 + 256 + tid]; }
  if (tanhFirst) { x0 = tanhf(x0); x1 = tanhf(x1); }
  float s = x0 + x1, ss = x0 * x0 + x1 * x1;
  #pragma unroll
  for (int off = 32; off > 0; off >>= 1) { s += __shfl_down(s, off); ss += __shfl_down(ss, off); }
  __shared__ float rs[4], rss[4];
  if ((tid & 63) == 0) { rs[tid >> 6] = s; rss[tid >> 6] = ss; }
  __syncthreads();
  float st = rs[0] + rs[1] + rs[2] + rs[3];
  float sst = rss[0] + rss[1] + rss[2] + rss[3];
  float mean = st * (1.0f / 512.0f);
  float var = sst * (1.0f / 512.0f) - mean * mean;
  float inv = rsqrtf(var + 1e-5f);
  float y0 = (x0 - mean) * inv * gv[tid] + bv[tid];
  float y1 = (x1 - mean) * inv * gv[256 + tid] + bv[256 + tid];
  if (!tanhFirst) { y0 = tanhf(y0); y1 = tanhf(y1); }
  dst[(size_t)m * ldd + dcoff + tid] = y0;
  dst[(size_t)m * ldd + dcoff + 256 + tid] = y1;
}

// inv-norm vector only: swn[r] = 16 / max(||soma_r||, 1e-12)
__global__ __launch_bounds__(256) void swinv_kernel(const float* __restrict__ soma,
                                                    float* __restrict__ swn) {
  int r = blockIdx.x, tid = threadIdx.x;
  float x0 = soma[(size_t)r * 512 + tid];
  float x1 = soma[(size_t)r * 512 + 256 + tid];
  float ss = x0 * x0 + x1 * x1;
  #pragma unroll
  for (int off = 32; off > 0; off >>= 1) ss += __shfl_down(ss, off);
  __shared__ float r4[4];
  if ((tid & 63) == 0) r4[tid >> 6] = ss;
  __syncthreads();
  if (tid == 0) {
    float norm = fmaxf(sqrtf(r4[0] + r4[1] + r4[2] + r4[3]), 1e-12f);
    swn[r] = 16.0f / norm;
  }
}

// ---------- host ----------
extern "C" void kernel_launch(void* const* d_in, const int* in_sizes, int n_in,
                              void* d_out, int out_size, void* d_ws, size_t ws_size,
                              hipStream_t stream) {
  (void)in_sizes; (void)n_in; (void)out_size; (void)ws_size;
  float* W = (float*)d_ws;
  float* outf = (float*)d_out;
  // out layout (floats): logits[262144] | thought[524288] | hf1[1024] | hs1[1024]
  const int* x = (const int*)d_in[0];
  const float* soma = (const float*)d_in[3];

  // Clear tagged rings + hsbuf + flags every launch (tags are 1-based and
  // monotone within a run; a previous run's tags would alias exactly).
  // ring 8192 + hsb 4096 + flags 4096 floats = 65536 bytes, contiguous.
  hipMemsetAsync((char*)d_ws + (size_t)OFF_RING * 4, 0, 65536, stream);
  hipMemsetAsync((char*)d_ws + (size_t)OFF_DEN * 4, 0, 4096, stream);

  // fused GRU1+GRU2 (speculative tag sweep + flag fallback; no producer drain)
  gru2_kernel<<<2 * L_WGS, 256, 0, stream>>>(soma, x,
      (const float*)d_in[4], (const float*)d_in[6],
      (const float*)d_in[5], (const float*)d_in[7], (const float*)d_in[1],
      (const float*)d_in[8], (const float*)d_in[10],
      (const float*)d_in[9], (const float*)d_in[11], (const float*)d_in[2],
      W + OFF_COMB, W + OFF_PS, outf + 786432, outf + 787456,
      (unsigned long long*)(W + OFF_RING), (unsigned long long*)(W + OFF_HSB),
      (unsigned*)(W + OFF_FLAGS),
      (unsigned*)(W + OFF_FLAGS) + L_WGS * FLAG_STRIDE);

  // merged: qkv (elu+1 on q,k) -> QKV ; gate pre -> TMP ; hip query -> QH
  gemm3<<<dim3(40, 16), 256, 0, stream>>>(W + OFF_PS,
      (const float*)d_in[12], (const float*)d_in[13],
      (const float*)d_in[14], (const float*)d_in[15],
      (const float*)d_in[19], (const float*)d_in[20],
      W + OFF_QKV, W + OFF_TMP, W + OFF_QH);

  // scores = causal(q k^T) per batch, row-sums fused -> DEN
  gemm<<<dim3(8, 16), 256, 0, stream>>>(W + OFF_QKV, 1536, W + OFF_QKV + 512, 1536,
      W + OFF_SCORES, 512, 0, 512, nullptr, nullptr, nullptr, W + OFF_DEN,
      1.f, F_CAUSAL | F_ROWSUM, 512, nullptr, 0);

  // l_mem = (scores @ v) / (den + 1e-6) -> combined cols [1024,1536)
  gemm<<<dim3(8, 16), 256, 0, stream>>>(W + OFF_SCORES, 512, W + OFF_QKV + 1024, 1536,
      W + OFF_COMB, 2048, 1024, 512, nullptr, W + OFF_DEN, nullptr, nullptr,
      1.f, F_NN | F_DIV, 512, nullptr, 0);

  // intent = tanh(LN(gate pre)) -> combined cols [512,1024)
  ln_kernel<<<1024, 256, 0, stream>>>(W + OFF_TMP, nullptr, W + OFF_COMB, 2048, 512,
      (const float*)d_in[16], (const float*)d_in[17], 0);

  // hippocampus attention -> combined cols [1536,2048)
  gemm<<<dim3(4, 16), 256, 0, stream>>>(W + OFF_QH, 512, (const float*)d_in[18], 512,
      W + OFF_ATTN, 256, 0, 512, nullptr, nullptr, nullptr, nullptr,
      0.04419417382415922f, F_SCALE, 0, nullptr, 0);
  softmax_kernel<<<1024, 256, 0, stream>>>(W + OFF_ATTN);
  gemm<<<dim3(8, 16), 256, 0, stream>>>(W + OFF_ATTN, 256, (const float*)d_in[18], 512,
      W + OFF_COMB, 2048, 1536, 256, nullptr, nullptr, nullptr, nullptr,
      1.f, F_NN, 0, nullptr, 0);

  // axon split-K x2 (one 256-block launch): k<1024 -> TMP (+bias), k>=1024 -> QH
  gemm<<<dim3(8, 16, 2), 256, 0, stream>>>(W + OFF_COMB, 2048, (const float*)d_in[21], 2048,
      W + OFF_TMP, 512, 0, 1024, (const float*)d_in[22], nullptr, nullptr, nullptr,
      1.f, 0, 0, W + OFF_QH, 1024);

  // thought = LN(tanh(TMP + QH)) -> out (fp32)
  ln_kernel<<<1024, 256, 0, stream>>>(W + OFF_TMP, W + OFF_QH, outf + 262144, 512, 0,
      (const float*)d_in[23], (const float*)d_in[24], 1);

  // logits = thought @ soma^T scaled by 16/||soma_n|| -> out (fp32)
  swinv_kernel<<<256, 256, 0, stream>>>(soma, W + OFF_SWN);
  gemm<<<dim3(4, 16), 256, 0, stream>>>(outf + 262144, 512, soma, 512,
      outf, 256, 0, 512, nullptr, nullptr, W + OFF_SWN, nullptr,
      1.f, 0, 0, nullptr, 0);
}

// Round 4
// 1739.288 us; speedup vs baseline: 1.0687x; 1.0687x over previous
//
#include <hip/hip_runtime.h>
#include <cstddef>

// B=2 T=512 D=512 V=256 MEM=256 ; M = B*T = 1024
// All inputs fp32 (x is int32); all outputs fp32.
#define F_ELUQK 1
#define F_CAUSAL 2
#define F_DIV 4
#define F_NN 8
#define F_SCALE 16
#define F_ROWSUM 32
#define FLAG_STRIDE 4    // u32 units -> 16 B per WG flag slot (packed: poll = 8 lines)
#define L_WGS 64         // WGs per GRU layer
#define UNITS 8          // hidden units per WG

// ---------- ws layout (float units) ----------
enum : int {
  OFF_QH = 0,                          // [1024][512] hip query / axon K-chunk-1 acc
  OFF_COMB = 524288,                   // [1024][2048]  p_f | intent | l_mem | episodes
  OFF_PS = OFF_COMB + 2097152,         // [1024][512]
  OFF_QKV = OFF_PS + 524288,           // [1024][1536]  q(elu+1) | k(elu+1) | v
  OFF_SCORES = OFF_QKV + 1572864,      // [1024][512]
  OFF_DEN = OFF_SCORES + 524288,       // [1024]
  OFF_TMP = OFF_DEN + 1024,            // [1024][512]
  OFF_ATTN = OFF_TMP + 524288,         // [1024][256]
  OFF_SWN = OFF_ATTN + 262144,         // [256] 16/||soma_row||
  OFF_RING = OFF_SWN + 256,            // ull[4][1024] tagged h_f ring (8192 floats)
  OFF_HSB = OFF_RING + 8192,           // ull[2][1024] tagged h_s dbuf (4096 floats)
  OFF_FLAGS = OFF_HSB + 4096           // flagsA[64*4] | flagsB[64*4] u32 (2 KB)
};

// raw workgroup barrier: LDS visibility only (lgkmcnt), NO vmcnt drain.
// Every LDS-writing wave drains its own lgkmcnt here; outstanding global
// stores (pf_out/ps_out, flag posts) stay in flight across it.
#define BAR() __asm__ __volatile__("s_waitcnt lgkmcnt(0)\n\ts_barrier" ::: "memory")

// ---------- generic tiled GEMM:  C[m, coff+n] = sum_k A(m,k) * B(n,k)  (+epilogue) ----------
__global__ __launch_bounds__(256) void gemm(
    const float* __restrict__ A, int lda, const float* __restrict__ B, int ldb,
    float* __restrict__ C, int ldc, int coff, int K,
    const float* __restrict__ bias, const float* __restrict__ den,
    const float* __restrict__ cscale, float* __restrict__ rsum,
    float scale, int flags, int bBatch,
    float* __restrict__ Cz, int kzoff) {
  __shared__ float As[16 * 65];
  __shared__ float Bs[16 * 65];
  int tid = threadIdx.x;
  int n0 = blockIdx.x * 64, m0 = blockIdx.y * 64;
  if (blockIdx.z) { A += kzoff; B += kzoff; C = Cz; bias = nullptr; }
  int rowoff = (m0 >> 9) * bBatch;
  int tx = tid & 15, ty = tid >> 4;

  if ((flags & F_CAUSAL) && n0 > ((m0 & 511) + 63)) {
    #pragma unroll
    for (int i = 0; i < 4; ++i)
      #pragma unroll
      for (int j = 0; j < 4; ++j)
        C[(size_t)(m0 + ty * 4 + i) * ldc + coff + n0 + tx * 4 + j] = 0.f;
    return;
  }

  float acc[4][4] = {};
  for (int k0 = 0; k0 < K; k0 += 16) {
    {
      int rr = tid >> 2, c4 = (tid & 3) << 2;
      const float* ap = A + (size_t)(m0 + rr) * lda + (k0 + c4);
      float4 av = *(const float4*)ap;
      As[(c4 + 0) * 65 + rr] = av.x;
      As[(c4 + 1) * 65 + rr] = av.y;
      As[(c4 + 2) * 65 + rr] = av.z;
      As[(c4 + 3) * 65 + rr] = av.w;
    }
    if (!(flags & F_NN)) {
      int rr = tid >> 2, c4 = (tid & 3) << 2;
      const float* bp = B + (size_t)(n0 + rr + rowoff) * ldb + (k0 + c4);
      float4 bv = *(const float4*)bp;
      Bs[(c4 + 0) * 65 + rr] = bv.x; Bs[(c4 + 1) * 65 + rr] = bv.y;
      Bs[(c4 + 2) * 65 + rr] = bv.z; Bs[(c4 + 3) * 65 + rr] = bv.w;
    } else {
      int kk = tid >> 4, n4 = (tid & 15) << 2;
      const float* bp = B + (size_t)(k0 + kk + rowoff) * ldb + (n0 + n4);
      float4 bv = *(const float4*)bp;
      Bs[kk * 65 + n4 + 0] = bv.x; Bs[kk * 65 + n4 + 1] = bv.y;
      Bs[kk * 65 + n4 + 2] = bv.z; Bs[kk * 65 + n4 + 3] = bv.w;
    }
    __syncthreads();
    #pragma unroll
    for (int k = 0; k < 16; ++k) {
      float av[4], bv[4];
      #pragma unroll
      for (int i = 0; i < 4; ++i) av[i] = As[k * 65 + ty * 4 + i];
      #pragma unroll
      for (int j = 0; j < 4; ++j) bv[j] = Bs[k * 65 + tx * 4 + j];
      #pragma unroll
      for (int i = 0; i < 4; ++i)
        #pragma unroll
        for (int j = 0; j < 4; ++j)
          acc[i][j] = fmaf(av[i], bv[j], acc[i][j]);
    }
    __syncthreads();
  }
  float rs[4] = {0.f, 0.f, 0.f, 0.f};
  #pragma unroll
  for (int i = 0; i < 4; ++i) {
    int m = m0 + ty * 4 + i;
    float dv = (flags & F_DIV) ? (1.0f / (den[m] + 1e-6f)) : 1.0f;
    #pragma unroll
    for (int j = 0; j < 4; ++j) {
      int n = n0 + tx * 4 + j;
      float v = acc[i][j];
      if (bias) v += bias[n];
      if (flags & F_ELUQK) { if (n < 1024) v = (v > 0.f) ? (v + 1.f) : __expf(v); }
      if (flags & F_CAUSAL) { if (n > (m & 511)) v = 0.f; }
      if (flags & F_SCALE) v *= scale;
      if (cscale) v *= cscale[coff + n];
      if (flags & F_DIV) v *= dv;
      C[(size_t)m * ldc + coff + n] = v;
      if (flags & F_ROWSUM) rs[i] += v;
    }
  }
  if (flags & F_ROWSUM) {
    #pragma unroll
    for (int i = 0; i < 4; ++i) {
      float s = rs[i];
      s += __shfl_xor(s, 1); s += __shfl_xor(s, 2);
      s += __shfl_xor(s, 4); s += __shfl_xor(s, 8);
      if (tx == 0) atomicAdd(rsum + (m0 + ty * 4 + i), s);
    }
  }
}

// ---------- merged qkv / gate / hip_q projections (A = PS, K=512, NT) ----------
__global__ __launch_bounds__(256) void gemm3(
    const float* __restrict__ A,
    const float* __restrict__ qkvw, const float* __restrict__ qkvb,
    const float* __restrict__ gatew, const float* __restrict__ gateb,
    const float* __restrict__ hipw, const float* __restrict__ hipb,
    float* __restrict__ QKV, float* __restrict__ TMP, float* __restrict__ QH) {
  __shared__ float As[16 * 65];
  __shared__ float Bs[16 * 65];
  int tid = threadIdx.x;
  int n0 = blockIdx.x * 64, m0 = blockIdx.y * 64;
  const float* B; const float* bias; float* C; int ldc, base;
  if (n0 < 1536) { B = qkvw; bias = qkvb; C = QKV; ldc = 1536; base = 0; }
  else if (n0 < 2048) { B = gatew; bias = gateb; C = TMP; ldc = 512; base = 1536; }
  else { B = hipw; bias = hipb; C = QH; ldc = 512; base = 2048; }
  int tx = tid & 15, ty = tid >> 4;
  float acc[4][4] = {};
  for (int k0 = 0; k0 < 512; k0 += 16) {
    {
      int rr = tid >> 2, c4 = (tid & 3) << 2;
      const float* ap = A + (size_t)(m0 + rr) * 512 + (k0 + c4);
      float4 av = *(const float4*)ap;
      As[(c4 + 0) * 65 + rr] = av.x; As[(c4 + 1) * 65 + rr] = av.y;
      As[(c4 + 2) * 65 + rr] = av.z; As[(c4 + 3) * 65 + rr] = av.w;
    }
    {
      int rr = tid >> 2, c4 = (tid & 3) << 2;
      const float* bp = B + (size_t)(n0 - base + rr) * 512 + (k0 + c4);
      float4 bv = *(const float4*)bp;
      Bs[(c4 + 0) * 65 + rr] = bv.x; Bs[(c4 + 1) * 65 + rr] = bv.y;
      Bs[(c4 + 2) * 65 + rr] = bv.z; Bs[(c4 + 3) * 65 + rr] = bv.w;
    }
    __syncthreads();
    #pragma unroll
    for (int k = 0; k < 16; ++k) {
      float av[4], bv[4];
      #pragma unroll
      for (int i = 0; i < 4; ++i) av[i] = As[k * 65 + ty * 4 + i];
      #pragma unroll
      for (int j = 0; j < 4; ++j) bv[j] = Bs[k * 65 + tx * 4 + j];
      #pragma unroll
      for (int i = 0; i < 4; ++i)
        #pragma unroll
        for (int j = 0; j < 4; ++j)
          acc[i][j] = fmaf(av[i], bv[j], acc[i][j]);
    }
    __syncthreads();
  }
  #pragma unroll
  for (int i = 0; i < 4; ++i) {
    int m = m0 + ty * 4 + i;
    #pragma unroll
    for (int j = 0; j < 4; ++j) {
      int n = n0 + tx * 4 + j;
      float v = acc[i][j] + bias[n - base];
      if (n < 1024) v = (v > 0.f) ? (v + 1.f) : __expf(v);
      C[(size_t)m * ldc + (n - base)] = v;
    }
  }
}

// ---------- flag helpers (relaxed agent ops only) ----------
__device__ __forceinline__ void post_flag(unsigned* flags, int w, unsigned v) {
  __hip_atomic_store(flags + (size_t)w * FLAG_STRIDE, v, __ATOMIC_RELAXED,
                     __HIP_MEMORY_SCOPE_AGENT);
}
__device__ __forceinline__ void poll64(const unsigned* flags, unsigned tgt, int lane) {
  const unsigned* p = flags + (size_t)lane * FLAG_STRIDE;
  while (__hip_atomic_load(p, __ATOMIC_RELAXED, __HIP_MEMORY_SCOPE_AGENT) < tgt)
    __builtin_amdgcn_s_sleep(1);
}
// stage_pull: ONE speculative tag-validated sweep; on a stale tag, fall back
// to the packed flag poll + validated retry loop. PRECONDITION for profit
// (round-3 lesson): the caller must have burned ~1 store-visibility latency
// of useful work since the producers' expected post time, else the sweep is
// systematically early and the spec read is wasted.
__device__ __forceinline__ void stage_pull(const unsigned long long* __restrict__ src,
                                           const unsigned* __restrict__ flags,
                                           unsigned tgt, int lane,
                                           float* __restrict__ dstLds) {
  unsigned long long v[16];
  #pragma unroll
  for (int k = 0; k < 16; ++k)
    v[k] = __hip_atomic_load(src + k * 64 + lane, __ATOMIC_RELAXED,
                             __HIP_MEMORY_SCOPE_AGENT);
  unsigned bad = 0;
  #pragma unroll
  for (int k = 0; k < 16; ++k) bad |= ((unsigned)(v[k] >> 32)) ^ tgt;
  if (!__all(bad == 0)) {
    poll64(flags, tgt, lane);
    for (;;) {
      #pragma unroll
      for (int k = 0; k < 16; ++k)
        v[k] = __hip_atomic_load(src + k * 64 + lane, __ATOMIC_RELAXED,
                                 __HIP_MEMORY_SCOPE_AGENT);
      bad = 0;
      #pragma unroll
      for (int k = 0; k < 16; ++k) bad |= ((unsigned)(v[k] >> 32)) ^ tgt;
      if (__all(bad == 0)) break;
      __builtin_amdgcn_s_sleep(1);
    }
  }
  #pragma unroll
  for (int k = 0; k < 16; ++k)
    dstLds[k * 64 + lane] = __uint_as_float((unsigned)v[k]);
}

// ---------- fused two-layer pipelined GRU, register-resident weights ----------
// 128 WGs: 0..63 layer1 (fast), 64..127 layer2 (slow, lags ~1-3 rounds).
// ROLES: waves 0-2 (r<24) = pure compute. wave 3 = stager+gates.
// ROUND-4 SCHEDULE: all remote pulls live in PHASE A, chained so each pull's
// latency is the delay that makes the NEXT pull's speculation reliable; phase
// B is compute-bound (wave3 idle or slack-poll only).
//   L1 phase A (wave3): prefetch s_in(t+1) -> inb (ds_write forces the vmcnt
//     wait; sched_barrier pins order) THEN spec-pull ring h(t-1) -> hl.
//   L2 phase A (wave3): spec-pull ring(t2+1) -> inb (tag posted by L1 ~a full
//     step earlier once L1 banks its 3-step lead -> spec hits) THEN spec-pull
//     hsq h_s(t2-1) -> hl (delayed by the ring pull -> spec hits).
//   phase B: waves0-2 gh-dot; L1 wave3 polls flagsB slack (off-chain).
//   gates: wave3 lanes<16 after B2: tagged stores + packed-flag post + out
//     stores; NO vmcnt drain anywhere in the loop (BAR = lgkmcnt only).
// Flags are packed at 16B stride: one poll attempt touches 8 cache lines
// instead of 64.
// Skew safety: identical happens-before edges as round 2 — tag==t validation
// proves every peer ran gates(t-1), hence passed phase A(t-1), hence consumed
// the data its gates(t) will overwrite. Ring slot t&3 overwrite still gated
// by flagsB(t-3); ring consumption moved EARLIER in L2's step (phase A), so
// the slack only loosens. 8B tagged values are single atomics (no tearing).
// Tags are 1-based; host zeroes ring/hsb/flags per launch.
__global__ __launch_bounds__(256, 1) void gru2_kernel(
    const float* __restrict__ soma, const int* __restrict__ x,
    const float* __restrict__ fwih, const float* __restrict__ fbih,
    const float* __restrict__ fwhh, const float* __restrict__ fbhh,
    const float* __restrict__ h0f,
    const float* __restrict__ swih, const float* __restrict__ sbih,
    const float* __restrict__ swhh, const float* __restrict__ sbhh,
    const float* __restrict__ h0s,
    float* __restrict__ pf_out,         // COMB cols [0,512), ld 2048
    float* __restrict__ ps_out,         // PS, ld 512
    float* __restrict__ hfT, float* __restrict__ hsT,
    unsigned long long* __restrict__ ringq,   // [4][1024] tagged h_f
    unsigned long long* __restrict__ hsq,     // [2][1024] tagged h_s
    unsigned* __restrict__ flagsA, unsigned* __restrict__ flagsB) {
  __shared__ __attribute__((aligned(16))) float hl[1024];    // own-layer h(t-1)
  __shared__ __attribute__((aligned(16))) float inb[2048];   // input dbuf (s_in or p_f)
  __shared__ float P[48];
  __shared__ float Q[48];
  __shared__ float bl[24];
  __shared__ float bi[24];
  __shared__ int xl[1024];
  int tid = threadIdx.x, wg = blockIdx.x;
  bool L1 = wg < L_WGS;
  int j0 = (wg & (L_WGS - 1)) * UNITS;
  int part = tid & 7, r = tid >> 3;    // r in 0..31; compute lanes r<24
  int g = r >> 3, u = r & 7;           // gate, unit
  int wave = tid >> 6, lane = tid & 63;
  const float* whh = L1 ? fwhh : swhh;
  const float* bhh = L1 ? fbhh : sbhh;
  const float* wih = L1 ? fwih : swih;
  const float* bih = L1 ? fbih : sbih;

  float4 wh[16], wi[16];
  if (r < 24) {
    const float* wp = whh + (size_t)(g * 512 + j0 + u) * 512 + part * 4;
    #pragma unroll
    for (int i = 0; i < 16; ++i) wh[i] = *(const float4*)(wp + i * 32);
    const float* wp2 = wih + (size_t)(g * 512 + j0 + u) * 512 + part * 4;
    #pragma unroll
    for (int i = 0; i < 16; ++i) wi[i] = *(const float4*)(wp2 + i * 32);
  }
  if (tid < 24) {
    bl[tid] = bhh[(tid >> 3) * 512 + j0 + (tid & 7)];
    bi[tid] = bih[(tid >> 3) * 512 + j0 + (tid & 7)];
  }
  if (L1) {
    for (int q = tid; q < 1024; q += 256) xl[q] = x[q];
  }
  __syncthreads();

  // ---- pre-stage inb slot 0 (input for step 0) by wave 3 ----
  if (wave == 3) {
    if (L1) {
      int r0 = xl[0], r1 = xl[512];
      const float4* sp0 = (const float4*)(soma + (size_t)r0 * 512);
      const float4* sp1 = (const float4*)(soma + (size_t)r1 * 512);
      float4* dst = (float4*)inb;
      dst[lane * 2] = sp0[lane * 2]; dst[lane * 2 + 1] = sp0[lane * 2 + 1];
      dst[128 + lane * 2] = sp1[lane * 2]; dst[128 + lane * 2 + 1] = sp1[lane * 2 + 1];
    } else {
      stage_pull(ringq, flagsA, 1u, lane, inb);   // ring(0) -> inb slot 0
    }
  }
  BAR();

  const float4* h4 = (const float4*)hl;

  if (L1) {
    for (int t = 0; t < 512; ++t) {
      float c0 = 0.f, c1 = 0.f;
      // ---- PHASE A: [prefetch s_in(t+1) -> spec stage h(t-1)] || gi-dot ----
      if (wave == 3) {
        if (t == 0) {
          #pragma unroll
          for (int k = 0; k < 16; ++k) hl[k * 64 + lane] = h0f[k * 64 + lane];
          int r0 = xl[1], r1 = xl[513];
          const float4* sp0 = (const float4*)(soma + (size_t)r0 * 512);
          const float4* sp1 = (const float4*)(soma + (size_t)r1 * 512);
          float4* dst = (float4*)(inb + 1024);
          dst[lane * 2] = sp0[lane * 2]; dst[lane * 2 + 1] = sp0[lane * 2 + 1];
          dst[128 + lane * 2] = sp1[lane * 2]; dst[128 + lane * 2 + 1] = sp1[lane * 2 + 1];
        } else {
          if (t + 1 < 512) {
            // prefetch burns the store-visibility latency AND does useful work
            int r0 = xl[t + 1], r1 = xl[512 + t + 1];
            const float4* sp0 = (const float4*)(soma + (size_t)r0 * 512);
            const float4* sp1 = (const float4*)(soma + (size_t)r1 * 512);
            float4* dst = (float4*)(inb + ((t + 1) & 1) * 1024);
            dst[lane * 2] = sp0[lane * 2]; dst[lane * 2 + 1] = sp0[lane * 2 + 1];
            dst[128 + lane * 2] = sp1[lane * 2];
            dst[128 + lane * 2 + 1] = sp1[lane * 2 + 1];
            __builtin_amdgcn_sched_barrier(0);   // keep sweep loads AFTER prefetch
          }
          stage_pull(ringq + (size_t)((t - 1) & 3) * 1024, flagsA,
                     (unsigned)t, lane, hl);
        }
      } else {
        const float4* f4v = (const float4*)(inb + (t & 1) * 1024);
        #pragma unroll
        for (int i = 0; i < 16; ++i) {
          float4 v = wi[i];
          float4 y0 = f4v[i * 8 + part];
          float4 y1 = f4v[128 + i * 8 + part];
          c0 += v.x * y0.x + v.y * y0.y + v.z * y0.z + v.w * y0.w;
          c1 += v.x * y1.x + v.y * y1.y + v.z * y1.z + v.w * y1.w;
        }
      }
      BAR();
      // ---- PHASE B: gh-dot + reduce || flagsB slack poll (off-chain) ----
      if (wave != 3) {
        float a0 = 0.f, a1 = 0.f;
        #pragma unroll
        for (int i = 0; i < 16; ++i) {
          float4 w = wh[i];
          float4 x0 = h4[i * 8 + part];
          float4 x1 = h4[128 + i * 8 + part];
          a0 += w.x * x0.x + w.y * x0.y + w.z * x0.z + w.w * x0.w;
          a1 += w.x * x1.x + w.y * x1.y + w.z * x1.z + w.w * x1.w;
        }
        a0 += __shfl_xor(a0, 1); a0 += __shfl_xor(a0, 2); a0 += __shfl_xor(a0, 4);
        a1 += __shfl_xor(a1, 1); a1 += __shfl_xor(a1, 2); a1 += __shfl_xor(a1, 4);
        c0 += __shfl_xor(c0, 1); c0 += __shfl_xor(c0, 2); c0 += __shfl_xor(c0, 4);
        c1 += __shfl_xor(c1, 1); c1 += __shfl_xor(c1, 2); c1 += __shfl_xor(c1, 4);
        if (part == 0) { P[r] = a0; P[24 + r] = a1; Q[r] = c0; Q[24 + r] = c1; }
      } else {
        if (t >= 4) poll64(flagsB, (unsigned)(t - 3), lane);   // ring slot free
      }
      BAR();
      // ---- GATES (wave3 lanes<16) — overlaps next phase A of waves0-2 ----
      if (wave == 3 && lane < 16) {
        int b = lane >> 3, u2 = lane & 7, j = j0 + u2;
        float i_r = Q[b * 24 + u2] + bi[u2];
        float i_z = Q[b * 24 + 8 + u2] + bi[8 + u2];
        float i_n = Q[b * 24 + 16 + u2] + bi[16 + u2];
        float gh_r = P[b * 24 + u2] + bl[u2];
        float gh_z = P[b * 24 + 8 + u2] + bl[8 + u2];
        float gh_n = P[b * 24 + 16 + u2] + bl[16 + u2];
        float hold = hl[b * 512 + j];
        float rg = 1.0f / (1.0f + __expf(-(i_r + gh_r)));
        float zg = 1.0f / (1.0f + __expf(-(i_z + gh_z)));
        float ng = tanhf(i_n + rg * gh_n);
        float hnew = (1.0f - zg) * ng + zg * hold;
        unsigned long long pv =
            ((unsigned long long)(unsigned)(t + 1) << 32) |
            (unsigned long long)__float_as_uint(hnew);
        __hip_atomic_store(ringq + (size_t)(t & 3) * 1024 + b * 512 + j, pv,
                           __ATOMIC_RELAXED, __HIP_MEMORY_SCOPE_AGENT);
        if (lane == 0) post_flag(flagsA, wg, (unsigned)(t + 1));
        pf_out[(size_t)(b * 512 + t) * 2048 + j] = hnew;
        if (t == 511) hfT[b * 512 + j] = hnew;
      }
      // no trailing barrier: wave3 flows into next phase-A staging; the next
      // B1 orders hl/P/Q reuse, and inb[(t+1)&1] writes drained at B1 above.
    }
  } else {
    for (int t2 = 0; t2 < 512; ++t2) {
      float c0 = 0.f, c1 = 0.f;
      // ---- PHASE A: [ring(t2+1) pull -> spec hsq stage] || gi-dot ----
      if (wave == 3) {
        if (t2 == 0) {
          #pragma unroll
          for (int k = 0; k < 16; ++k) hl[k * 64 + lane] = h0s[k * 64 + lane];
        }
        if (t2 + 1 < 512) {
          // L1 posted tag t2+2 ~a full step ago (3-step lead) -> spec hits;
          // this pull's latency is the delay that makes the hsq spec reliable
          stage_pull(ringq + (size_t)((t2 + 1) & 3) * 1024, flagsA,
                     (unsigned)(t2 + 2), lane, inb + ((t2 + 1) & 1) * 1024);
          __builtin_amdgcn_sched_barrier(0);     // keep hsq sweep AFTER ring pull
        }
        if (t2 > 0) {
          stage_pull(hsq + (size_t)((t2 - 1) & 1) * 1024, flagsB,
                     (unsigned)t2, lane, hl);
        }
      } else {
        const float4* f4v = (const float4*)(inb + (t2 & 1) * 1024);
        #pragma unroll
        for (int i = 0; i < 16; ++i) {
          float4 v = wi[i];
          float4 y0 = f4v[i * 8 + part];
          float4 y1 = f4v[128 + i * 8 + part];
          c0 += v.x * y0.x + v.y * y0.y + v.z * y0.z + v.w * y0.w;
          c1 += v.x * y1.x + v.y * y1.y + v.z * y1.z + v.w * y1.w;
        }
      }
      BAR();
      // ---- PHASE B: gh-dot + reduce (wave3 idle) ----
      if (wave != 3) {
        float a0 = 0.f, a1 = 0.f;
        #pragma unroll
        for (int i = 0; i < 16; ++i) {
          float4 w = wh[i];
          float4 x0 = h4[i * 8 + part];
          float4 x1 = h4[128 + i * 8 + part];
          a0 += w.x * x0.x + w.y * x0.y + w.z * x0.z + w.w * x0.w;
          a1 += w.x * x1.x + w.y * x1.y + w.z * x1.z + w.w * x1.w;
        }
        a0 += __shfl_xor(a0, 1); a0 += __shfl_xor(a0, 2); a0 += __shfl_xor(a0, 4);
        a1 += __shfl_xor(a1, 1); a1 += __shfl_xor(a1, 2); a1 += __shfl_xor(a1, 4);
        c0 += __shfl_xor(c0, 1); c0 += __shfl_xor(c0, 2); c0 += __shfl_xor(c0, 4);
        c1 += __shfl_xor(c1, 1); c1 += __shfl_xor(c1, 2); c1 += __shfl_xor(c1, 4);
        if (part == 0) { P[r] = a0; P[24 + r] = a1; Q[r] = c0; Q[24 + r] = c1; }
      }
      BAR();
      // ---- GATES (wave3 lanes<16) ----
      if (wave == 3 && lane < 16) {
        int b = lane >> 3, u2 = lane & 7, j = j0 + u2;
        float i_r = Q[b * 24 + u2] + bi[u2];
        float i_z = Q[b * 24 + 8 + u2] + bi[8 + u2];
        float i_n = Q[b * 24 + 16 + u2] + bi[16 + u2];
        float gh_r = P[b * 24 + u2] + bl[u2];
        float gh_z = P[b * 24 + 8 + u2] + bl[8 + u2];
        float gh_n = P[b * 24 + 16 + u2] + bl[16 + u2];
        float hold = hl[b * 512 + j];
        float rg = 1.0f / (1.0f + __expf(-(i_r + gh_r)));
        float zg = 1.0f / (1.0f + __expf(-(i_z + gh_z)));
        float ng = tanhf(i_n + rg * gh_n);
        float hnew = (1.0f - zg) * ng + zg * hold;
        unsigned long long pv =
            ((unsigned long long)(unsigned)(t2 + 1) << 32) |
            (unsigned long long)__float_as_uint(hnew);
        __hip_atomic_store(hsq + (size_t)(t2 & 1) * 1024 + b * 512 + j, pv,
                           __ATOMIC_RELAXED, __HIP_MEMORY_SCOPE_AGENT);
        if (lane == 0) post_flag(flagsB, wg - L_WGS, (unsigned)(t2 + 1));
        ps_out[(size_t)(b * 512 + t2) * 512 + j] = hnew;
        if (t2 == 511) hsT[b * 512 + j] = hnew;
      }
    }
  }
}

// ---------- small kernels ----------
__global__ __launch_bounds__(256) void softmax_kernel(float* __restrict__ a) {
  int m = blockIdx.x, tid = threadIdx.x;
  float v = a[(size_t)m * 256 + tid];
  float mx = v;
  #pragma unroll
  for (int off = 32; off > 0; off >>= 1) mx = fmaxf(mx, __shfl_down(mx, off));
  __shared__ float r4[4];
  __shared__ float s4[4];
  if ((tid & 63) == 0) r4[tid >> 6] = mx;
  __syncthreads();
  mx = fmaxf(fmaxf(r4[0], r4[1]), fmaxf(r4[2], r4[3]));
  float e = __expf(v - mx);
  float s = e;
  #pragma unroll
  for (int off = 32; off > 0; off >>= 1) s += __shfl_down(s, off);
  if ((tid & 63) == 0) s4[tid >> 6] = s;
  __syncthreads();
  s = s4[0] + s4[1] + s4[2] + s4[3];
  a[(size_t)m * 256 + tid] = e / s;
}

__global__ __launch_bounds__(256) void ln_kernel(
    const float* __restrict__ src, const float* __restrict__ src2,
    float* __restrict__ dst, int ldd, int dcoff,
    const float* __restrict__ gv, const float* __restrict__ bv, int tanhFirst) {
  int m = blockIdx.x, tid = threadIdx.x;
  float x0 = src[(size_t)m * 512 + tid];
  float x1 = src[(size_t)m * 512 + 256 + tid];
  if (src2) { x0 += src2[(size_t)m * 512 + tid]; x1 += src2[(size_t)m * 512 + 256 + tid]; }
  if (tanhFirst) { x0 = tanhf(x0); x1 = tanhf(x1); }
  float s = x0 + x1, ss = x0 * x0 + x1 * x1;
  #pragma unroll
  for (int off = 32; off > 0; off >>= 1) { s += __shfl_down(s, off); ss += __shfl_down(ss, off); }
  __shared__ float rs[4], rss[4];
  if ((tid & 63) == 0) { rs[tid >> 6] = s; rss[tid >> 6] = ss; }
  __syncthreads();
  float st = rs[0] + rs[1] + rs[2] + rs[3];
  float sst = rss[0] + rss[1] + rss[2] + rss[3];
  float mean = st * (1.0f / 512.0f);
  float var = sst * (1.0f / 512.0f) - mean * mean;
  float inv = rsqrtf(var + 1e-5f);
  float y0 = (x0 - mean) * inv * gv[tid] + bv[tid];
  float y1 = (x1 - mean) * inv * gv[256 + tid] + bv[256 + tid];
  if (!tanhFirst) { y0 = tanhf(y0); y1 = tanhf(y1); }
  dst[(size_t)m * ldd + dcoff + tid] = y0;
  dst[(size_t)m * ldd + dcoff + 256 + tid] = y1;
}

// inv-norm vector only: swn[r] = 16 / max(||soma_r||, 1e-12)
__global__ __launch_bounds__(256) void swinv_kernel(const float* __restrict__ soma,
                                                    float* __restrict__ swn) {
  int r = blockIdx.x, tid = threadIdx.x;
  float x0 = soma[(size_t)r * 512 + tid];
  float x1 = soma[(size_t)r * 512 + 256 + tid];
  float ss = x0 * x0 + x1 * x1;
  #pragma unroll
  for (int off = 32; off > 0; off >>= 1) ss += __shfl_down(ss, off);
  __shared__ float r4[4];
  if ((tid & 63) == 0) r4[tid >> 6] = ss;
  __syncthreads();
  if (tid == 0) {
    float norm = fmaxf(sqrtf(r4[0] + r4[1] + r4[2] + r4[3]), 1e-12f);
    swn[r] = 16.0f / norm;
  }
}

// ---------- host ----------
extern "C" void kernel_launch(void* const* d_in, const int* in_sizes, int n_in,
                              void* d_out, int out_size, void* d_ws, size_t ws_size,
                              hipStream_t stream) {
  (void)in_sizes; (void)n_in; (void)out_size; (void)ws_size;
  float* W = (float*)d_ws;
  float* outf = (float*)d_out;
  // out layout (floats): logits[262144] | thought[524288] | hf1[1024] | hs1[1024]
  const int* x = (const int*)d_in[0];
  const float* soma = (const float*)d_in[3];

  // Clear tagged rings + hsbuf + packed flags every launch (tags are 1-based
  // and monotone within a run; a previous run's tags would alias exactly).
  // ring 8192 + hsb 4096 + flags 512 floats = 51200 bytes, contiguous.
  hipMemsetAsync((char*)d_ws + (size_t)OFF_RING * 4, 0, 51200, stream);
  hipMemsetAsync((char*)d_ws + (size_t)OFF_DEN * 4, 0, 4096, stream);

  // fused GRU1+GRU2 (phase-A chained pulls, packed flags, no producer drain)
  gru2_kernel<<<2 * L_WGS, 256, 0, stream>>>(soma, x,
      (const float*)d_in[4], (const float*)d_in[6],
      (const float*)d_in[5], (const float*)d_in[7], (const float*)d_in[1],
      (const float*)d_in[8], (const float*)d_in[10],
      (const float*)d_in[9], (const float*)d_in[11], (const float*)d_in[2],
      W + OFF_COMB, W + OFF_PS, outf + 786432, outf + 787456,
      (unsigned long long*)(W + OFF_RING), (unsigned long long*)(W + OFF_HSB),
      (unsigned*)(W + OFF_FLAGS),
      (unsigned*)(W + OFF_FLAGS) + L_WGS * FLAG_STRIDE);

  // merged: qkv (elu+1 on q,k) -> QKV ; gate pre -> TMP ; hip query -> QH
  gemm3<<<dim3(40, 16), 256, 0, stream>>>(W + OFF_PS,
      (const float*)d_in[12], (const float*)d_in[13],
      (const float*)d_in[14], (const float*)d_in[15],
      (const float*)d_in[19], (const float*)d_in[20],
      W + OFF_QKV, W + OFF_TMP, W + OFF_QH);

  // scores = causal(q k^T) per batch, row-sums fused -> DEN
  gemm<<<dim3(8, 16), 256, 0, stream>>>(W + OFF_QKV, 1536, W + OFF_QKV + 512, 1536,
      W + OFF_SCORES, 512, 0, 512, nullptr, nullptr, nullptr, W + OFF_DEN,
      1.f, F_CAUSAL | F_ROWSUM, 512, nullptr, 0);

  // l_mem = (scores @ v) / (den + 1e-6) -> combined cols [1024,1536)
  gemm<<<dim3(8, 16), 256, 0, stream>>>(W + OFF_SCORES, 512, W + OFF_QKV + 1024, 1536,
      W + OFF_COMB, 2048, 1024, 512, nullptr, W + OFF_DEN, nullptr, nullptr,
      1.f, F_NN | F_DIV, 512, nullptr, 0);

  // intent = tanh(LN(gate pre)) -> combined cols [512,1024)
  ln_kernel<<<1024, 256, 0, stream>>>(W + OFF_TMP, nullptr, W + OFF_COMB, 2048, 512,
      (const float*)d_in[16], (const float*)d_in[17], 0);

  // hippocampus attention -> combined cols [1536,2048)
  gemm<<<dim3(4, 16), 256, 0, stream>>>(W + OFF_QH, 512, (const float*)d_in[18], 512,
      W + OFF_ATTN, 256, 0, 512, nullptr, nullptr, nullptr, nullptr,
      0.04419417382415922f, F_SCALE, 0, nullptr, 0);
  softmax_kernel<<<1024, 256, 0, stream>>>(W + OFF_ATTN);
  gemm<<<dim3(8, 16), 256, 0, stream>>>(W + OFF_ATTN, 256, (const float*)d_in[18], 512,
      W + OFF_COMB, 2048, 1536, 256, nullptr, nullptr, nullptr, nullptr,
      1.f, F_NN, 0, nullptr, 0);

  // axon split-K x2 (one 256-block launch): k<1024 -> TMP (+bias), k>=1024 -> QH
  gemm<<<dim3(8, 16, 2), 256, 0, stream>>>(W + OFF_COMB, 2048, (const float*)d_in[21], 2048,
      W + OFF_TMP, 512, 0, 1024, (const float*)d_in[22], nullptr, nullptr, nullptr,
      1.f, 0, 0, W + OFF_QH, 1024);

  // thought = LN(tanh(TMP + QH)) -> out (fp32)
  ln_kernel<<<1024, 256, 0, stream>>>(W + OFF_TMP, W + OFF_QH, outf + 262144, 512, 0,
      (const float*)d_in[23], (const float*)d_in[24], 1);

  // logits = thought @ soma^T scaled by 16/||soma_n|| -> out (fp32)
  swinv_kernel<<<256, 256, 0, stream>>>(soma, W + OFF_SWN);
  gemm<<<dim3(4, 16), 256, 0, stream>>>(outf + 262144, 512, soma, 512,
      outf, 256, 0, 512, nullptr, nullptr, W + OFF_SWN, nullptr,
      1.f, 0, 0, nullptr, 0);
}